// Round 8
// baseline (1845.346 us; speedup 1.0000x reference)
//
#include <hip/hip_runtime.h>
#include <hip/hip_bf16.h>

#define N_NODES 50000
#define N_EDGES 400000
#define N_GRAPH 256
#define HID 256
#define DEPTH 6

typedef float f32x4 __attribute__((ext_vector_type(4)));
typedef int   i32x4 __attribute__((ext_vector_type(4)));

__device__ __forceinline__ float bf2f(unsigned short u) {
  unsigned v = ((unsigned)u) << 16;
  return __builtin_bit_cast(float, v);
}
__device__ __forceinline__ unsigned short f2bf(float f) {
  unsigned u = __builtin_bit_cast(unsigned, f);
  u += 0x7fffu + ((u >> 16) & 1u);  // RNE
  return (unsigned short)(u >> 16);
}
__device__ __forceinline__ float bflo(unsigned u) {
  return __builtin_bit_cast(float, u << 16);
}
__device__ __forceinline__ float bfhi(unsigned u) {
  return __builtin_bit_cast(float, u & 0xffff0000u);
}

__device__ __forceinline__ float block_sum256(float v, float* lds) {
#pragma unroll
  for (int off = 32; off > 0; off >>= 1) v += __shfl_down(v, off, 64);
  int w = threadIdx.x >> 6;
  if ((threadIdx.x & 63) == 0) lds[w] = v;
  __syncthreads();
  float r = lds[0] + lds[1] + lds[2] + lds[3];
  __syncthreads();
  return r;
}

__global__ __launch_bounds__(256) void k_deg(const int* __restrict__ src, const int* __restrict__ dst,
                                             int* deg_out, int* deg_in) {
  int e = blockIdx.x * 256 + threadIdx.x;
  if (e < N_EDGES) { atomicAdd(&deg_out[src[e]], 1); atomicAdd(&deg_in[dst[e]], 1); }
}

__global__ __launch_bounds__(256) void k_norm(const int* deg_out, const int* deg_in,
                                              float* norm_o, float* norm_i) {
  int i = blockIdx.x * 256 + threadIdx.x;
  if (i < N_NODES) {
    int dO = deg_out[i], dI = deg_in[i];
    norm_o[i] = dO > 0 ? rsqrtf((float)dO) : 0.f;
    norm_i[i] = dI > 0 ? rsqrtf((float)dI) : 0.f;
  }
}

__global__ __launch_bounds__(256) void k_scan1(const int* deg_in, int* partial) {
  int i = blockIdx.x * 256 + threadIdx.x;
  int v = (i < N_NODES) ? deg_in[i] : 0;
#pragma unroll
  for (int off = 32; off > 0; off >>= 1) v += __shfl_down(v, off, 64);
  __shared__ int l[4];
  if ((threadIdx.x & 63) == 0) l[threadIdx.x >> 6] = v;
  __syncthreads();
  if (threadIdx.x == 0) partial[blockIdx.x] = l[0] + l[1] + l[2] + l[3];
}

__global__ __launch_bounds__(256) void k_scan2(const int* partial, int* chunk_off, int* row_start, int nb) {
  __shared__ int ss[256];
  int t = threadIdx.x;
  int v = (t < nb) ? partial[t] : 0;
  ss[t] = v; __syncthreads();
#pragma unroll
  for (int off = 1; off < 256; off <<= 1) {
    int x = ss[t];
    int y = (t >= off) ? ss[t - off] : 0;
    __syncthreads();
    ss[t] = x + y;
    __syncthreads();
  }
  if (t < nb) chunk_off[t] = ss[t] - v;
  if (t == 0) row_start[N_NODES] = N_EDGES;
}

__global__ __launch_bounds__(256) void k_scan3(const int* deg_in, const int* chunk_off, int* row_start) {
  __shared__ int ss[256];
  int t = threadIdx.x;
  int i = blockIdx.x * 256 + t;
  int v = (i < N_NODES) ? deg_in[i] : 0;
  ss[t] = v; __syncthreads();
#pragma unroll
  for (int off = 1; off < 256; off <<= 1) {
    int x = ss[t];
    int y = (t >= off) ? ss[t - off] : 0;
    __syncthreads();
    ss[t] = x + y;
    __syncthreads();
  }
  if (i < N_NODES) row_start[i] = chunk_off[blockIdx.x] + ss[t] - v;
}

__global__ __launch_bounds__(256) void k_fill(const int* src, const int* dst, const int* row_start,
                                              int* cursor, int* csr_src) {
  int e = blockIdx.x * 256 + threadIdx.x;
  if (e < N_EDGES) {
    int d = dst[e];
    int p = atomicAdd(&cursor[d], 1);
    csr_src[row_start[d] + p] = src[e];
  }
}

// Edge-parallel e_t aggregation: esum[n][16] = sum over edges with dst=n.
__global__ __launch_bounds__(256) void k_esum(const float* __restrict__ e_t, const int* __restrict__ dst,
                                              float* esum) {
  int t = blockIdx.x * 256 + threadIdx.x;
  int e = t >> 4, ch = t & 15;
  if (e < N_EDGES) atomicAdd(&esum[(size_t)dst[e] * 16 + ch], e_t[(size_t)e * 16 + ch]);
}

// Transpose + bf16-convert all 12 layer weights: Wt[li][n][k] = W[li][k][n]
__global__ __launch_bounds__(256) void k_wt(const float* __restrict__ Wc1, const float* __restrict__ Wc2,
                                            unsigned short* __restrict__ Wt) {
  __shared__ float tile[32][33];
  int li = blockIdx.z;
  const float* W = ((li & 1) ? Wc2 : Wc1) + (size_t)(li >> 1) * HID * HID;
  int k0 = blockIdx.x * 32, n0 = blockIdx.y * 32;
  int tx = threadIdx.x & 31, ty = threadIdx.x >> 5;
#pragma unroll
  for (int r = ty; r < 32; r += 8) tile[r][tx] = W[(size_t)(k0 + r) * HID + n0 + tx];
  __syncthreads();
  unsigned short* outp = Wt + (size_t)li * HID * HID;
#pragma unroll
  for (int r = ty; r < 32; r += 8) outp[(size_t)(n0 + r) * HID + k0 + tx] = f2bf(tile[tx][r]);
}

// Pack z[n][32] = concat(a,c,x)[27] * norm_o[n]  (pad to 32 f32, lanes 27..31 = 0)
__global__ __launch_bounds__(256) void k_z(const float* __restrict__ a, const float* __restrict__ c,
                                           const float* __restrict__ x, const float* __restrict__ norm_o,
                                           float* __restrict__ z) {
  int t = blockIdx.x * 256 + threadIdx.x;
  int n = t >> 5, lane = t & 31;
  if (n >= N_NODES) return;
  float v = 0.f;
  if (lane < 16) v = a[(size_t)n * 16 + lane];
  else if (lane < 24) v = c[(size_t)n * 8 + (lane - 16)];
  else if (lane < 27) v = x[(size_t)n * 3 + (lane - 24)];
  z[(size_t)n * 32 + lane] = v * norm_o[n];
}

// Input layer: wave per node; z-gather 8 edges per instruction (f32x4/lane, 8 lanes per
// 128B row, group = lane>>3 picks edge); e-contribution from precomputed esum.
// Epilogue K=43 matvec -> hf(bf16), Af.
__global__ __launch_bounds__(256) void k_in(const float* __restrict__ z, const float* __restrict__ esum,
                                            const int* __restrict__ csr_src, const int* __restrict__ rs,
                                            const float* __restrict__ norm_o, const float* __restrict__ norm_i,
                                            const float* __restrict__ W_in, const float* __restrict__ b_in,
                                            const float* __restrict__ W_e, const float* __restrict__ b_e,
                                            unsigned short* __restrict__ hf, unsigned short* __restrict__ Af) {
  int w = threadIdx.x >> 6, lane = threadIdx.x & 63;
  int n = blockIdx.x * 4 + w;  // 50000 % 4 == 0
  int g = lane >> 3, c4 = lane & 7;
  __shared__ float zs[4][32];
  __shared__ float es[4][16];
  if (lane >= 32 && lane < 48) es[w][lane - 32] = esum[(size_t)n * 16 + (lane - 32)];
  int beg = rs[n], end = rs[n + 1];
  f32x4 acc = {0.f, 0.f, 0.f, 0.f};
  for (int p = beg + g; p < end; p += 8) {
    int s = csr_src[p];
    acc += *(const f32x4*)(z + (size_t)s * 32 + c4 * 4);
  }
#pragma unroll
  for (int m = 8; m < 64; m <<= 1) {
#pragma unroll
    for (int k = 0; k < 4; ++k) acc[k] += __shfl_xor(acc[k], m, 64);
  }
  if (g == 0) {
#pragma unroll
    for (int k = 0; k < 4; ++k) zs[w][c4 * 4 + k] = acc[k];
  }
  __syncthreads();
  float degf = (float)(end - beg);
  float invd = 1.f / fmaxf(degf, 1.f);
  float niv = norm_i[n], nov = norm_o[n];
#pragma unroll
  for (int i = 0; i < 4; ++i) {
    int cc = lane + 64 * i;
    float da = 0.f, de = 0.f;
#pragma unroll
    for (int k = 0; k < 27; ++k) da += zs[w][k] * W_in[k * HID + cc];
#pragma unroll
    for (int k = 0; k < 16; ++k) de += es[w][k] * W_e[k * HID + cc];
    float val = da * niv + b_in[cc] + (de + degf * b_e[cc]) * invd;
    hf[(size_t)n * HID + cc] = f2bf(val);
    Af[(size_t)n * HID + cc] = f2bf(val * nov);
  }
}

// Fused layer, 8-row tile, 512 threads, wave-per-row gather with 2-edges-per-
// instruction (dwordx4: half = lane>>5 picks edge, ch16 = lane&31 picks 16B chunk),
// 4-deep unroll = 8 edges in flight; MFMA GEMM (M=16, rows 8..15 zeroed);
// epilogue norm_i+b -> LN (cross-wave) -> SiLU -> (+res, bf16 hf) -> AfN.
// Af / AfN must be distinct buffers (inter-block WAR race).
template <int RES>
__global__ __launch_bounds__(512) void k_layer(const unsigned short* __restrict__ Af,
                                               const int* __restrict__ csr_src, const int* __restrict__ rs,
                                               const unsigned short* __restrict__ Bt,
                                               const float* __restrict__ norm_i,
                                               const float* __restrict__ norm_o,
                                               const float* __restrict__ b, const float* __restrict__ g,
                                               const float* __restrict__ be,
                                               unsigned short* __restrict__ hf,
                                               unsigned short* __restrict__ AfN) {
  const int LDA = HID + 8;  // pad 16B
  __shared__ unsigned short As[16 * LDA];
  __shared__ float red1[8][8], red2[8][8];
  int wave = threadIdx.x >> 6, lane = threadIdx.x & 63;
  int l15 = lane & 15, quad = lane >> 4;
  int n0 = blockIdx.x * 8;  // 50000 = 8 * 6250, exact
  int half = lane >> 5, ch16 = lane & 31;
  int boff = ch16 * 8;  // ushort offset of this lane's 16B chunk
  // zero MFMA rows 8..15 (row 8+wave)
  {
    ushort4 zz = {0, 0, 0, 0};
    *(ushort4*)(&As[(size_t)(8 + wave) * LDA + lane * 4]) = zz;
  }
  // ---- gather: wave handles row n0+wave; halves interleave edges ----
  int n = n0 + wave;
  int beg = rs[n], end = rs[n + 1];
  float a0 = 0.f, a1 = 0.f, a2 = 0.f, a3 = 0.f, a4 = 0.f, a5 = 0.f, a6 = 0.f, a7 = 0.f;
  int p = beg + half;
  for (; p + 6 < end; p += 8) {  // this half covers edges p, p+2, p+4, p+6
    int s0 = csr_src[p], s1 = csr_src[p + 2], s2 = csr_src[p + 4], s3 = csr_src[p + 6];
    i32x4 v0 = *(const i32x4*)(Af + (size_t)s0 * HID + boff);
    i32x4 v1 = *(const i32x4*)(Af + (size_t)s1 * HID + boff);
    i32x4 v2 = *(const i32x4*)(Af + (size_t)s2 * HID + boff);
    i32x4 v3 = *(const i32x4*)(Af + (size_t)s3 * HID + boff);
#pragma unroll
    for (int k = 0; k < 4; ++k) {
      unsigned u0 = (unsigned)v0[k], u1 = (unsigned)v1[k], u2 = (unsigned)v2[k], u3 = (unsigned)v3[k];
      float lo = bflo(u0) + bflo(u1) + bflo(u2) + bflo(u3);
      float hi = bfhi(u0) + bfhi(u1) + bfhi(u2) + bfhi(u3);
      if (k == 0) { a0 += lo; a1 += hi; }
      else if (k == 1) { a2 += lo; a3 += hi; }
      else if (k == 2) { a4 += lo; a5 += hi; }
      else { a6 += lo; a7 += hi; }
    }
  }
  for (; p < end; p += 2) {
    i32x4 v = *(const i32x4*)(Af + (size_t)csr_src[p] * HID + boff);
    a0 += bflo(v[0]); a1 += bfhi(v[0]);
    a2 += bflo(v[1]); a3 += bfhi(v[1]);
    a4 += bflo(v[2]); a5 += bfhi(v[2]);
    a6 += bflo(v[3]); a7 += bfhi(v[3]);
  }
  // combine the two halves
  a0 += __shfl_xor(a0, 32, 64); a1 += __shfl_xor(a1, 32, 64);
  a2 += __shfl_xor(a2, 32, 64); a3 += __shfl_xor(a3, 32, 64);
  a4 += __shfl_xor(a4, 32, 64); a5 += __shfl_xor(a5, 32, 64);
  a6 += __shfl_xor(a6, 32, 64); a7 += __shfl_xor(a7, 32, 64);
  if (half == 0) {
    ushort4 o0, o1;
    o0.x = f2bf(a0); o0.y = f2bf(a1); o0.z = f2bf(a2); o0.w = f2bf(a3);
    o1.x = f2bf(a4); o1.y = f2bf(a5); o1.z = f2bf(a6); o1.w = f2bf(a7);
    *(ushort4*)(&As[(size_t)wave * LDA + boff]) = o0;
    *(ushort4*)(&As[(size_t)wave * LDA + boff + 4]) = o1;
  }
  __syncthreads();
  // ---- GEMM: wave covers cols [wave*32, wave*32+32), rows n0..n0+7 (8..15 zero) ----
  const unsigned short* asp = &As[(size_t)l15 * LDA + quad * 8];
  const unsigned short* bp = Bt + (size_t)(wave * 32 + l15) * HID + quad * 8;
  f32x4 acc[2] = {};
  asm volatile("s_nop 7\n\ts_nop 7" : "+v"(acc[0]), "+v"(acc[1]));
#pragma unroll
  for (int k0 = 0; k0 < HID; k0 += 32) {
    i32x4 af = *(const i32x4*)(asp + k0);
#pragma unroll
    for (int t = 0; t < 2; ++t) {
      i32x4 bt = *(const i32x4*)(bp + (size_t)t * 16 * HID + k0);
      asm volatile("v_mfma_f32_16x16x32_bf16 %0, %1, %2, %0" : "+v"(acc[t]) : "v"(af), "v"(bt));
    }
  }
  asm volatile("s_nop 7\n\ts_nop 7\n\ts_nop 7" : "+v"(acc[0]), "+v"(acc[1]));
  // C/D layout: col = wave*32 + t*16 + l15, local row rl = quad*4 + j (valid rl < 8)
  float ni[4];
#pragma unroll
  for (int j = 0; j < 4; ++j) {
    int rl = quad * 4 + j;
    ni[j] = norm_i[n0 + (rl & 7)];
  }
#pragma unroll
  for (int t = 0; t < 2; ++t) {
    int ct = wave * 32 + t * 16 + l15;
    float bv = b[ct];
#pragma unroll
    for (int j = 0; j < 4; ++j) acc[t][j] = acc[t][j] * ni[j] + bv;
  }
  float s1[4] = {0.f, 0.f, 0.f, 0.f}, s2[4] = {0.f, 0.f, 0.f, 0.f};
#pragma unroll
  for (int t = 0; t < 2; ++t)
#pragma unroll
    for (int j = 0; j < 4; ++j) { s1[j] += acc[t][j]; s2[j] += acc[t][j] * acc[t][j]; }
#pragma unroll
  for (int m = 1; m < 16; m <<= 1) {
#pragma unroll
    for (int j = 0; j < 4; ++j) {
      s1[j] += __shfl_xor(s1[j], m, 16);
      s2[j] += __shfl_xor(s2[j], m, 16);
    }
  }
  if (l15 == 0 && quad < 2) {
#pragma unroll
    for (int j = 0; j < 4; ++j) {
      red1[wave][quad * 4 + j] = s1[j];
      red2[wave][quad * 4 + j] = s2[j];
    }
  }
  __syncthreads();
  float mu[4], inv[4];
#pragma unroll
  for (int j = 0; j < 4; ++j) {
    int rl = (quad * 4 + j) & 7;
    float t1 = 0.f, t2 = 0.f;
#pragma unroll
    for (int ww = 0; ww < 8; ++ww) { t1 += red1[ww][rl]; t2 += red2[ww][rl]; }
    mu[j] = t1 * (1.f / HID);
    float var = t2 * (1.f / HID) - mu[j] * mu[j];
    inv[j] = rsqrtf(var + 1e-5f);
  }
  if (quad < 2) {
#pragma unroll
    for (int j = 0; j < 4; ++j) {
      int r = n0 + quad * 4 + j;
      float nov = norm_o[r];
      unsigned short* hrow = hf + (size_t)r * HID;
      unsigned short* an = AfN + (size_t)r * HID;
#pragma unroll
      for (int t = 0; t < 2; ++t) {
        int ct = wave * 32 + t * 16 + l15;
        float oo = (acc[t][j] - mu[j]) * inv[j] * g[ct] + be[ct];
        float sl = oo * (1.f / (1.f + __expf(-oo)));
        float outv = sl;
        if (RES) {
          outv = sl + bf2f(hrow[ct]);
          hrow[ct] = f2bf(outv);
        }
        an[ct] = f2bf(outv * nov);
      }
    }
  }
}

// Fused mean-pool + head, no atomics: gid is sorted, one block per graph.
__global__ __launch_bounds__(256) void k_poolhead(const unsigned short* __restrict__ hf,
                                                  const int* __restrict__ gid,
                                                  const float* __restrict__ Wh, const float* __restrict__ bh,
                                                  float* __restrict__ out) {
  int gg = blockIdx.x, ch = threadIdx.x;
  int lo = 0, hi = N_NODES;
  while (lo < hi) { int mid = (lo + hi) >> 1; if (gid[mid] < gg) lo = mid + 1; else hi = mid; }
  int beg = lo;
  hi = N_NODES;
  while (lo < hi) { int mid = (lo + hi) >> 1; if (gid[mid] < gg + 1) lo = mid + 1; else hi = mid; }
  int end = lo;
  float s = 0.f;
  int n = beg;
  for (; n + 4 <= end; n += 4) {
    s += bf2f(hf[(size_t)n * HID + ch]) + bf2f(hf[(size_t)(n + 1) * HID + ch]) +
         bf2f(hf[(size_t)(n + 2) * HID + ch]) + bf2f(hf[(size_t)(n + 3) * HID + ch]);
  }
  for (; n < end; ++n) s += bf2f(hf[(size_t)n * HID + ch]);
  float v = s * Wh[ch];
  __shared__ float l[4];
  float tot = block_sum256(v, l);
  if (ch == 0) {
    float c = fmaxf((float)(end - beg), 1.f);
    float xx = tot / c + bh[0];
    out[gg] = fmaxf(xx, 0.f) + log1pf(expf(-fabsf(xx)));  // stable softplus
  }
}

extern "C" void kernel_launch(void* const* d_in, const int* in_sizes, int n_in,
                              void* d_out, int out_size, void* d_ws, size_t ws_size,
                              hipStream_t stream) {
  const float* a_t = (const float*)d_in[0];
  const float* c_t = (const float*)d_in[1];
  const float* x_t = (const float*)d_in[2];
  const float* e_t = (const float*)d_in[3];
  const int* src = (const int*)d_in[4];
  const int* dst = (const int*)d_in[5];
  const int* gid = (const int*)d_in[6];
  const float* W_in = (const float*)d_in[7];
  const float* b_in = (const float*)d_in[8];
  const float* W_e  = (const float*)d_in[9];
  const float* b_e  = (const float*)d_in[10];
  const float* Wc1  = (const float*)d_in[11];
  const float* bc1  = (const float*)d_in[12];
  const float* g1   = (const float*)d_in[13];
  const float* be1  = (const float*)d_in[14];
  const float* Wc2  = (const float*)d_in[15];
  const float* bc2  = (const float*)d_in[16];
  const float* g2   = (const float*)d_in[17];
  const float* be2  = (const float*)d_in[18];
  const float* W_head = (const float*)d_in[19];
  const float* b_head = (const float*)d_in[20];
  float* out = (float*)d_out;

  char* base = (char*)d_ws;
  size_t off = 0;
  auto carve = [&](size_t bytes) -> void* {
    void* p = base + off;
    off += (bytes + 255) & ~(size_t)255;
    return p;
  };
  int*   deg_out = (int*)carve((size_t)N_NODES * 4);
  int*   deg_in  = (int*)carve((size_t)N_NODES * 4);
  int*   cursor  = (int*)carve((size_t)N_NODES * 4);
  float* esum    = (float*)carve((size_t)N_NODES * 16 * 4);
  size_t zbytes = off;  // zeroed each call
  float* norm_o  = (float*)carve((size_t)N_NODES * 4);
  float* norm_i  = (float*)carve((size_t)N_NODES * 4);
  int*   row_start = (int*)carve((size_t)(N_NODES + 1) * 4);
  int*   partial   = (int*)carve(256 * 4);
  int*   chunk_off = (int*)carve(256 * 4);
  int*   csr_src   = (int*)carve((size_t)N_EDGES * 4);
  unsigned short* Wt = (unsigned short*)carve((size_t)2 * DEPTH * HID * HID * 2);
  float* zpack = (float*)carve((size_t)N_NODES * 32 * 4);
  unsigned short* hf = (unsigned short*)carve((size_t)N_NODES * HID * 2);
  unsigned short* Af0 = (unsigned short*)carve((size_t)N_NODES * HID * 2);
  unsigned short* Af1 = (unsigned short*)carve((size_t)N_NODES * HID * 2);
  (void)ws_size; (void)in_sizes; (void)n_in; (void)out_size;

  hipMemsetAsync(d_ws, 0, zbytes, stream);

  int ebl = (N_EDGES + 255) / 256;
  int nbl = (N_NODES + 255) / 256;
  k_deg<<<ebl, 256, 0, stream>>>(src, dst, deg_out, deg_in);
  k_norm<<<nbl, 256, 0, stream>>>(deg_out, deg_in, norm_o, norm_i);
  k_scan1<<<nbl, 256, 0, stream>>>(deg_in, partial);
  k_scan2<<<1, 256, 0, stream>>>(partial, chunk_off, row_start, nbl);
  k_scan3<<<nbl, 256, 0, stream>>>(deg_in, chunk_off, row_start);
  k_fill<<<ebl, 256, 0, stream>>>(src, dst, row_start, cursor, csr_src);
  k_esum<<<(N_EDGES * 16 + 255) / 256, 256, 0, stream>>>(e_t, dst, esum);
  k_wt<<<dim3(8, 8, 2 * DEPTH), 256, 0, stream>>>(Wc1, Wc2, Wt);
  k_z<<<(N_NODES * 32 + 255) / 256, 256, 0, stream>>>(a_t, c_t, x_t, norm_o, zpack);
  k_in<<<N_NODES / 4, 256, 0, stream>>>(zpack, esum, csr_src, row_start,
                                        norm_o, norm_i, W_in, b_in, W_e, b_e, hf, Af0);
  int gbl = N_NODES / 8;  // 6250, exact
  for (int d = 0; d < DEPTH; ++d) {
    // ping-pong: Af0 -> Af1 -> Af0 (read and write buffers must differ)
    k_layer<0><<<gbl, 512, 0, stream>>>(Af0, csr_src, row_start, Wt + (size_t)(2 * d) * HID * HID,
                                        norm_i, norm_o, bc1 + d * HID, g1 + d * HID, be1 + d * HID, hf, Af1);
    k_layer<1><<<gbl, 512, 0, stream>>>(Af1, csr_src, row_start, Wt + (size_t)(2 * d + 1) * HID * HID,
                                        norm_i, norm_o, bc2 + d * HID, g2 + d * HID, be2 + d * HID, hf, Af0);
  }
  k_poolhead<<<N_GRAPH, 256, 0, stream>>>(hf, gid, W_head, b_head, out);
}

// Round 9
// 1442.020 us; speedup vs baseline: 1.2797x; 1.2797x over previous
//
#include <hip/hip_runtime.h>
#include <hip/hip_bf16.h>

#define N_NODES 50000
#define N_EDGES 400000
#define N_GRAPH 256
#define HID 256
#define DEPTH 6

typedef float f32x4 __attribute__((ext_vector_type(4)));
typedef int   i32x4 __attribute__((ext_vector_type(4)));

__device__ __forceinline__ float bf2f(unsigned short u) {
  unsigned v = ((unsigned)u) << 16;
  return __builtin_bit_cast(float, v);
}
__device__ __forceinline__ unsigned short f2bf(float f) {
  unsigned u = __builtin_bit_cast(unsigned, f);
  u += 0x7fffu + ((u >> 16) & 1u);  // RNE
  return (unsigned short)(u >> 16);
}

__device__ __forceinline__ float block_sum256(float v, float* lds) {
#pragma unroll
  for (int off = 32; off > 0; off >>= 1) v += __shfl_down(v, off, 64);
  int w = threadIdx.x >> 6;
  if ((threadIdx.x & 63) == 0) lds[w] = v;
  __syncthreads();
  float r = lds[0] + lds[1] + lds[2] + lds[3];
  __syncthreads();
  return r;
}

__global__ __launch_bounds__(256) void k_deg(const int* __restrict__ src, const int* __restrict__ dst,
                                             int* deg_out, int* deg_in) {
  int e = blockIdx.x * 256 + threadIdx.x;
  if (e < N_EDGES) { atomicAdd(&deg_out[src[e]], 1); atomicAdd(&deg_in[dst[e]], 1); }
}

__global__ __launch_bounds__(256) void k_norm(const int* deg_out, const int* deg_in,
                                              float* norm_o, float* norm_i) {
  int i = blockIdx.x * 256 + threadIdx.x;
  if (i < N_NODES) {
    int dO = deg_out[i], dI = deg_in[i];
    norm_o[i] = dO > 0 ? rsqrtf((float)dO) : 0.f;
    norm_i[i] = dI > 0 ? rsqrtf((float)dI) : 0.f;
  }
}

__global__ __launch_bounds__(256) void k_scan1(const int* deg_in, int* partial) {
  int i = blockIdx.x * 256 + threadIdx.x;
  int v = (i < N_NODES) ? deg_in[i] : 0;
#pragma unroll
  for (int off = 32; off > 0; off >>= 1) v += __shfl_down(v, off, 64);
  __shared__ int l[4];
  if ((threadIdx.x & 63) == 0) l[threadIdx.x >> 6] = v;
  __syncthreads();
  if (threadIdx.x == 0) partial[blockIdx.x] = l[0] + l[1] + l[2] + l[3];
}

__global__ __launch_bounds__(256) void k_scan2(const int* partial, int* chunk_off, int* row_start, int nb) {
  __shared__ int ss[256];
  int t = threadIdx.x;
  int v = (t < nb) ? partial[t] : 0;
  ss[t] = v; __syncthreads();
#pragma unroll
  for (int off = 1; off < 256; off <<= 1) {
    int x = ss[t];
    int y = (t >= off) ? ss[t - off] : 0;
    __syncthreads();
    ss[t] = x + y;
    __syncthreads();
  }
  if (t < nb) chunk_off[t] = ss[t] - v;
  if (t == 0) row_start[N_NODES] = N_EDGES;
}

__global__ __launch_bounds__(256) void k_scan3(const int* deg_in, const int* chunk_off, int* row_start) {
  __shared__ int ss[256];
  int t = threadIdx.x;
  int i = blockIdx.x * 256 + t;
  int v = (i < N_NODES) ? deg_in[i] : 0;
  ss[t] = v; __syncthreads();
#pragma unroll
  for (int off = 1; off < 256; off <<= 1) {
    int x = ss[t];
    int y = (t >= off) ? ss[t - off] : 0;
    __syncthreads();
    ss[t] = x + y;
    __syncthreads();
  }
  if (i < N_NODES) row_start[i] = chunk_off[blockIdx.x] + ss[t] - v;
}

__global__ __launch_bounds__(256) void k_fill(const int* src, const int* dst, const int* row_start,
                                              int* cursor, int* csr_src) {
  int e = blockIdx.x * 256 + threadIdx.x;
  if (e < N_EDGES) {
    int d = dst[e];
    int p = atomicAdd(&cursor[d], 1);
    csr_src[row_start[d] + p] = src[e];
  }
}

// Edge-parallel e_t aggregation: esum[n][16] = sum over edges with dst=n.
__global__ __launch_bounds__(256) void k_esum(const float* __restrict__ e_t, const int* __restrict__ dst,
                                              float* esum) {
  int t = blockIdx.x * 256 + threadIdx.x;
  int e = t >> 4, ch = t & 15;
  if (e < N_EDGES) atomicAdd(&esum[(size_t)dst[e] * 16 + ch], e_t[(size_t)e * 16 + ch]);
}

// Transpose + bf16-convert all 12 layer weights: Wt[li][n][k] = W[li][k][n]
__global__ __launch_bounds__(256) void k_wt(const float* __restrict__ Wc1, const float* __restrict__ Wc2,
                                            unsigned short* __restrict__ Wt) {
  __shared__ float tile[32][33];
  int li = blockIdx.z;
  const float* W = ((li & 1) ? Wc2 : Wc1) + (size_t)(li >> 1) * HID * HID;
  int k0 = blockIdx.x * 32, n0 = blockIdx.y * 32;
  int tx = threadIdx.x & 31, ty = threadIdx.x >> 5;
#pragma unroll
  for (int r = ty; r < 32; r += 8) tile[r][tx] = W[(size_t)(k0 + r) * HID + n0 + tx];
  __syncthreads();
  unsigned short* outp = Wt + (size_t)li * HID * HID;
#pragma unroll
  for (int r = ty; r < 32; r += 8) outp[(size_t)(n0 + r) * HID + k0 + tx] = f2bf(tile[tx][r]);
}

// Pack z[n][32] = concat(a,c,x)[27] * norm_o[n]  (pad to 32 f32, lanes 27..31 = 0)
__global__ __launch_bounds__(256) void k_z(const float* __restrict__ a, const float* __restrict__ c,
                                           const float* __restrict__ x, const float* __restrict__ norm_o,
                                           float* __restrict__ z) {
  int t = blockIdx.x * 256 + threadIdx.x;
  int n = t >> 5, lane = t & 31;
  if (n >= N_NODES) return;
  float v = 0.f;
  if (lane < 16) v = a[(size_t)n * 16 + lane];
  else if (lane < 24) v = c[(size_t)n * 8 + (lane - 16)];
  else if (lane < 27) v = x[(size_t)n * 3 + (lane - 24)];
  z[(size_t)n * 32 + lane] = v * norm_o[n];
}

// Input layer: wave per node; z-gather 8 edges per instruction (f32x4/lane, 8 lanes per
// 128B row, group = lane>>3 picks edge); e-contribution from precomputed esum.
// Epilogue K=43 matvec -> hf(bf16, NT store), Af.
__global__ __launch_bounds__(256) void k_in(const float* __restrict__ z, const float* __restrict__ esum,
                                            const int* __restrict__ csr_src, const int* __restrict__ rs,
                                            const float* __restrict__ norm_o, const float* __restrict__ norm_i,
                                            const float* __restrict__ W_in, const float* __restrict__ b_in,
                                            const float* __restrict__ W_e, const float* __restrict__ b_e,
                                            unsigned short* __restrict__ hf, unsigned short* __restrict__ Af) {
  int w = threadIdx.x >> 6, lane = threadIdx.x & 63;
  int n = blockIdx.x * 4 + w;  // 50000 % 4 == 0
  int g = lane >> 3, c4 = lane & 7;
  __shared__ float zs[4][32];
  __shared__ float es[4][16];
  if (lane >= 32 && lane < 48) es[w][lane - 32] = esum[(size_t)n * 16 + (lane - 32)];
  int beg = rs[n], end = rs[n + 1];
  f32x4 acc = {0.f, 0.f, 0.f, 0.f};
  for (int p = beg + g; p < end; p += 8) {
    int s = csr_src[p];
    acc += *(const f32x4*)(z + (size_t)s * 32 + c4 * 4);
  }
#pragma unroll
  for (int m = 8; m < 64; m <<= 1) {
#pragma unroll
    for (int k = 0; k < 4; ++k) acc[k] += __shfl_xor(acc[k], m, 64);
  }
  if (g == 0) {
#pragma unroll
    for (int k = 0; k < 4; ++k) zs[w][c4 * 4 + k] = acc[k];
  }
  __syncthreads();
  float degf = (float)(end - beg);
  float invd = 1.f / fmaxf(degf, 1.f);
  float niv = norm_i[n], nov = norm_o[n];
#pragma unroll
  for (int i = 0; i < 4; ++i) {
    int cc = lane + 64 * i;
    float da = 0.f, de = 0.f;
#pragma unroll
    for (int k = 0; k < 27; ++k) da += zs[w][k] * W_in[k * HID + cc];
#pragma unroll
    for (int k = 0; k < 16; ++k) de += es[w][k] * W_e[k * HID + cc];
    float val = da * niv + b_in[cc] + (de + degf * b_e[cc]) * invd;
    __builtin_nontemporal_store(f2bf(val), &hf[(size_t)n * HID + cc]);
    Af[(size_t)n * HID + cc] = f2bf(val * nov);
  }
}

// Fused layer (R6 structure — best measured): 16-row tile, 512 threads (8 waves);
// each wave gathers 2 adjacent CSR rows in ONE flat edge loop (8-deep ushort4
// unroll, wave-uniform row split), then a 32-col slice of the [16,256]@[256,256]
// GEMM; epilogue norm_i+b -> LN (cross-wave) -> SiLU -> (+res, bf16 hf NT) -> AfN.
// Af / AfN must be distinct buffers (inter-block WAR race).
template <int RES>
__global__ __launch_bounds__(512) void k_layer(const unsigned short* __restrict__ Af,
                                               const int* __restrict__ csr_src, const int* __restrict__ rs,
                                               const unsigned short* __restrict__ Bt,
                                               const float* __restrict__ norm_i,
                                               const float* __restrict__ norm_o,
                                               const float* __restrict__ b, const float* __restrict__ g,
                                               const float* __restrict__ be,
                                               unsigned short* __restrict__ hf,
                                               unsigned short* __restrict__ AfN) {
  const int LDA = HID + 8;  // pad: keeps ds_read_b128 A-frags cheap
  __shared__ unsigned short As[16 * LDA];
  __shared__ float red1[8][16], red2[8][16];
  int wave = threadIdx.x >> 6, lane = threadIdx.x & 63;
  int l15 = lane & 15, quad = lane >> 4;
  int n0 = blockIdx.x * 16;  // 50000 = 16 * 3125, exact
  int off = lane * 4;
  // ---- gather: wave handles rows r0 = wave*2 and r0+1 in one flat loop ----
  int r0 = wave * 2;
  int beg = rs[n0 + r0], mid = rs[n0 + r0 + 1], end = rs[n0 + r0 + 2];
  float lo0 = 0.f, lo1 = 0.f, lo2 = 0.f, lo3 = 0.f;
  float hi0 = 0.f, hi1 = 0.f, hi2 = 0.f, hi3 = 0.f;
  int p = beg;
  for (; p + 8 <= end; p += 8) {
    int s[8];
#pragma unroll
    for (int q = 0; q < 8; ++q) s[q] = csr_src[p + q];
    ushort4 rr[8];
#pragma unroll
    for (int q = 0; q < 8; ++q) rr[q] = *(const ushort4*)(Af + (size_t)s[q] * HID + off);
#pragma unroll
    for (int q = 0; q < 8; ++q) {
      float v0 = bf2f(rr[q].x), v1 = bf2f(rr[q].y), v2 = bf2f(rr[q].z), v3 = bf2f(rr[q].w);
      if (p + q >= mid) { hi0 += v0; hi1 += v1; hi2 += v2; hi3 += v3; }  // wave-uniform branch
      else             { lo0 += v0; lo1 += v1; lo2 += v2; lo3 += v3; }
    }
  }
  for (; p < end; ++p) {
    ushort4 r = *(const ushort4*)(Af + (size_t)csr_src[p] * HID + off);
    float v0 = bf2f(r.x), v1 = bf2f(r.y), v2 = bf2f(r.z), v3 = bf2f(r.w);
    if (p >= mid) { hi0 += v0; hi1 += v1; hi2 += v2; hi3 += v3; }
    else          { lo0 += v0; lo1 += v1; lo2 += v2; lo3 += v3; }
  }
  ushort4 o;
  o.x = f2bf(lo0); o.y = f2bf(lo1); o.z = f2bf(lo2); o.w = f2bf(lo3);
  *(ushort4*)(&As[(size_t)r0 * LDA + off]) = o;
  o.x = f2bf(hi0); o.y = f2bf(hi1); o.z = f2bf(hi2); o.w = f2bf(hi3);
  *(ushort4*)(&As[(size_t)(r0 + 1) * LDA + off]) = o;
  __syncthreads();
  // ---- GEMM: wave covers cols [wave*32, wave*32+32), rows n0..n0+15 ----
  const unsigned short* asp = &As[(size_t)l15 * LDA + quad * 8];
  const unsigned short* bp = Bt + (size_t)(wave * 32 + l15) * HID + quad * 8;
  f32x4 acc[2] = {};
  asm volatile("s_nop 7\n\ts_nop 7" : "+v"(acc[0]), "+v"(acc[1]));
#pragma unroll
  for (int k0 = 0; k0 < HID; k0 += 32) {
    i32x4 af = *(const i32x4*)(asp + k0);
#pragma unroll
    for (int t = 0; t < 2; ++t) {
      i32x4 bt = *(const i32x4*)(bp + (size_t)t * 16 * HID + k0);
      asm volatile("v_mfma_f32_16x16x32_bf16 %0, %1, %2, %0" : "+v"(acc[t]) : "v"(af), "v"(bt));
    }
  }
  asm volatile("s_nop 7\n\ts_nop 7\n\ts_nop 7" : "+v"(acc[0]), "+v"(acc[1]));
  // C/D layout: col (within slice) = t*16 + l15, row = quad*4 + j
  float ni[4];
#pragma unroll
  for (int j = 0; j < 4; ++j) ni[j] = norm_i[n0 + quad * 4 + j];
#pragma unroll
  for (int t = 0; t < 2; ++t) {
    int ct = wave * 32 + t * 16 + l15;
    float bv = b[ct];
#pragma unroll
    for (int j = 0; j < 4; ++j) acc[t][j] = acc[t][j] * ni[j] + bv;
  }
  float s1[4] = {0.f, 0.f, 0.f, 0.f}, s2[4] = {0.f, 0.f, 0.f, 0.f};
#pragma unroll
  for (int t = 0; t < 2; ++t)
#pragma unroll
    for (int j = 0; j < 4; ++j) { s1[j] += acc[t][j]; s2[j] += acc[t][j] * acc[t][j]; }
#pragma unroll
  for (int m = 1; m < 16; m <<= 1) {
#pragma unroll
    for (int j = 0; j < 4; ++j) {
      s1[j] += __shfl_xor(s1[j], m, 16);
      s2[j] += __shfl_xor(s2[j], m, 16);
    }
  }
  if (l15 == 0) {
#pragma unroll
    for (int j = 0; j < 4; ++j) {
      red1[wave][quad * 4 + j] = s1[j];
      red2[wave][quad * 4 + j] = s2[j];
    }
  }
  __syncthreads();
  float mu[4], inv[4];
#pragma unroll
  for (int j = 0; j < 4; ++j) {
    int r = quad * 4 + j;
    float t1 = 0.f, t2 = 0.f;
#pragma unroll
    for (int ww = 0; ww < 8; ++ww) { t1 += red1[ww][r]; t2 += red2[ww][r]; }
    mu[j] = t1 * (1.f / HID);
    float var = t2 * (1.f / HID) - mu[j] * mu[j];
    inv[j] = rsqrtf(var + 1e-5f);
  }
#pragma unroll
  for (int j = 0; j < 4; ++j) {
    int r = n0 + quad * 4 + j;
    float nov = norm_o[r];
    unsigned short* hrow = hf + (size_t)r * HID;
    unsigned short* an = AfN + (size_t)r * HID;
#pragma unroll
    for (int t = 0; t < 2; ++t) {
      int ct = wave * 32 + t * 16 + l15;
      float oo = (acc[t][j] - mu[j]) * inv[j] * g[ct] + be[ct];
      float sl = oo * (1.f / (1.f + __expf(-oo)));
      float outv = sl;
      if (RES) {
        outv = sl + bf2f(hrow[ct]);
        __builtin_nontemporal_store(f2bf(outv), &hrow[ct]);
      }
      an[ct] = f2bf(outv * nov);
    }
  }
}

// Fused mean-pool + head, no atomics: gid is sorted, one block per graph.
__global__ __launch_bounds__(256) void k_poolhead(const unsigned short* __restrict__ hf,
                                                  const int* __restrict__ gid,
                                                  const float* __restrict__ Wh, const float* __restrict__ bh,
                                                  float* __restrict__ out) {
  int gg = blockIdx.x, ch = threadIdx.x;
  int lo = 0, hi = N_NODES;
  while (lo < hi) { int mid = (lo + hi) >> 1; if (gid[mid] < gg) lo = mid + 1; else hi = mid; }
  int beg = lo;
  hi = N_NODES;
  while (lo < hi) { int mid = (lo + hi) >> 1; if (gid[mid] < gg + 1) lo = mid + 1; else hi = mid; }
  int end = lo;
  float s = 0.f;
  int n = beg;
  for (; n + 4 <= end; n += 4) {
    s += bf2f(hf[(size_t)n * HID + ch]) + bf2f(hf[(size_t)(n + 1) * HID + ch]) +
         bf2f(hf[(size_t)(n + 2) * HID + ch]) + bf2f(hf[(size_t)(n + 3) * HID + ch]);
  }
  for (; n < end; ++n) s += bf2f(hf[(size_t)n * HID + ch]);
  float v = s * Wh[ch];
  __shared__ float l[4];
  float tot = block_sum256(v, l);
  if (ch == 0) {
    float c = fmaxf((float)(end - beg), 1.f);
    float xx = tot / c + bh[0];
    out[gg] = fmaxf(xx, 0.f) + log1pf(expf(-fabsf(xx)));  // stable softplus
  }
}

extern "C" void kernel_launch(void* const* d_in, const int* in_sizes, int n_in,
                              void* d_out, int out_size, void* d_ws, size_t ws_size,
                              hipStream_t stream) {
  const float* a_t = (const float*)d_in[0];
  const float* c_t = (const float*)d_in[1];
  const float* x_t = (const float*)d_in[2];
  const float* e_t = (const float*)d_in[3];
  const int* src = (const int*)d_in[4];
  const int* dst = (const int*)d_in[5];
  const int* gid = (const int*)d_in[6];
  const float* W_in = (const float*)d_in[7];
  const float* b_in = (const float*)d_in[8];
  const float* W_e  = (const float*)d_in[9];
  const float* b_e  = (const float*)d_in[10];
  const float* Wc1  = (const float*)d_in[11];
  const float* bc1  = (const float*)d_in[12];
  const float* g1   = (const float*)d_in[13];
  const float* be1  = (const float*)d_in[14];
  const float* Wc2  = (const float*)d_in[15];
  const float* bc2  = (const float*)d_in[16];
  const float* g2   = (const float*)d_in[17];
  const float* be2  = (const float*)d_in[18];
  const float* W_head = (const float*)d_in[19];
  const float* b_head = (const float*)d_in[20];
  float* out = (float*)d_out;

  char* base = (char*)d_ws;
  size_t off = 0;
  auto carve = [&](size_t bytes) -> void* {
    void* p = base + off;
    off += (bytes + 255) & ~(size_t)255;
    return p;
  };
  int*   deg_out = (int*)carve((size_t)N_NODES * 4);
  int*   deg_in  = (int*)carve((size_t)N_NODES * 4);
  int*   cursor  = (int*)carve((size_t)N_NODES * 4);
  float* esum    = (float*)carve((size_t)N_NODES * 16 * 4);
  size_t zbytes = off;  // zeroed each call
  float* norm_o  = (float*)carve((size_t)N_NODES * 4);
  float* norm_i  = (float*)carve((size_t)N_NODES * 4);
  int*   row_start = (int*)carve((size_t)(N_NODES + 1) * 4);
  int*   partial   = (int*)carve(256 * 4);
  int*   chunk_off = (int*)carve(256 * 4);
  int*   csr_src   = (int*)carve((size_t)N_EDGES * 4);
  unsigned short* Wt = (unsigned short*)carve((size_t)2 * DEPTH * HID * HID * 2);
  float* zpack = (float*)carve((size_t)N_NODES * 32 * 4);
  unsigned short* hf = (unsigned short*)carve((size_t)N_NODES * HID * 2);
  unsigned short* Af0 = (unsigned short*)carve((size_t)N_NODES * HID * 2);
  unsigned short* Af1 = (unsigned short*)carve((size_t)N_NODES * HID * 2);
  (void)ws_size; (void)in_sizes; (void)n_in; (void)out_size;

  hipMemsetAsync(d_ws, 0, zbytes, stream);

  int ebl = (N_EDGES + 255) / 256;
  int nbl = (N_NODES + 255) / 256;
  k_deg<<<ebl, 256, 0, stream>>>(src, dst, deg_out, deg_in);
  k_norm<<<nbl, 256, 0, stream>>>(deg_out, deg_in, norm_o, norm_i);
  k_scan1<<<nbl, 256, 0, stream>>>(deg_in, partial);
  k_scan2<<<1, 256, 0, stream>>>(partial, chunk_off, row_start, nbl);
  k_scan3<<<nbl, 256, 0, stream>>>(deg_in, chunk_off, row_start);
  k_fill<<<ebl, 256, 0, stream>>>(src, dst, row_start, cursor, csr_src);
  k_esum<<<(N_EDGES * 16 + 255) / 256, 256, 0, stream>>>(e_t, dst, esum);
  k_wt<<<dim3(8, 8, 2 * DEPTH), 256, 0, stream>>>(Wc1, Wc2, Wt);
  k_z<<<(N_NODES * 32 + 255) / 256, 256, 0, stream>>>(a_t, c_t, x_t, norm_o, zpack);
  k_in<<<N_NODES / 4, 256, 0, stream>>>(zpack, esum, csr_src, row_start,
                                        norm_o, norm_i, W_in, b_in, W_e, b_e, hf, Af0);
  int gbl = N_NODES / 16;  // 3125, exact
  for (int d = 0; d < DEPTH; ++d) {
    // ping-pong: Af0 -> Af1 -> Af0 (read and write buffers must differ)
    k_layer<0><<<gbl, 512, 0, stream>>>(Af0, csr_src, row_start, Wt + (size_t)(2 * d) * HID * HID,
                                        norm_i, norm_o, bc1 + d * HID, g1 + d * HID, be1 + d * HID, hf, Af1);
    k_layer<1><<<gbl, 512, 0, stream>>>(Af1, csr_src, row_start, Wt + (size_t)(2 * d + 1) * HID * HID,
                                        norm_i, norm_o, bc2 + d * HID, g2 + d * HID, be2 + d * HID, hf, Af0);
  }
  k_poolhead<<<N_GRAPH, 256, 0, stream>>>(hf, gid, W_head, b_head, out);
}